// Round 5
// baseline (256.149 us; speedup 1.0000x reference)
//
#include <hip/hip_runtime.h>
#include <math.h>

// Problem constants: B=16, N=128, M=64, D=512, H=4, K=128, L=3

// Workspace layout (floats)
#define OFF_W   0                         // w[bn][d]            : 2048*512
#define OFF_R   (2048*512)                // r[b*64+m][d]        : 1024*512
#define OFF_V   (OFF_R + 1024*512)        // v[d][h]             : 512*4
#define OFF_G   (OFF_V + 2048)            // G[b][h][d]          : 16*4*512
#define OFF_SW  (OFF_G + 32768)           // SW[b][h]            : 16*4
#define OFF_SC  (OFF_SW + 64)             // g_scratch[bn][h][d] : 2048*2048

// ---------------------------------------------------------------------------
// Kernel 1: fused projections + prep_v + zero G/SW
// 32x64 tiles: blocks [0,512): w, [512,768): r, [768,776): prep
// 256 threads, 2x4 microtile, BK=16, register-prefetch pipeline.
// ---------------------------------------------------------------------------
__global__ __launch_bounds__(256) void proj_gemm(
    const float* __restrict__ word, const float* __restrict__ rel,
    const float* __restrict__ Wn_w, const float* __restrict__ Wn_b,
    const float* __restrict__ Wr_w, const float* __restrict__ Wr_b,
    const float* __restrict__ lin_w, const float* __restrict__ score_w,
    float* __restrict__ ws)
{
    int blk = blockIdx.x;
    const int t = threadIdx.x;

    if (blk >= 768) {
        int gid = (blk - 768) * 256 + t;          // 0..2047
        float* Gz = ws + OFF_G + gid * 16;
        float4 z = make_float4(0.f, 0.f, 0.f, 0.f);
        *(float4*)(Gz + 0)  = z; *(float4*)(Gz + 4)  = z;
        *(float4*)(Gz + 8)  = z; *(float4*)(Gz + 12) = z;
        if (gid < 64) ws[OFF_SW + gid] = 0.f;
        int h = gid >> 9, d = gid & 511;
        const float* lw = lin_w + (size_t)(h * 512 + d) * 128;
        const float* sw = score_w + h * 128;
        float acc = 0.f;
        #pragma unroll 8
        for (int k = 0; k < 128; k += 4) {
            float4 a = *(const float4*)(lw + k);
            float4 bq = *(const float4*)(sw + k);
            acc = fmaf(a.x, bq.x, acc); acc = fmaf(a.y, bq.y, acc);
            acc = fmaf(a.z, bq.z, acc); acc = fmaf(a.w, bq.w, acc);
        }
        ws[OFF_V + d * 4 + h] = acc;
        return;
    }

    const float *A, *W, *bias;
    float* C;
    int rowTile, colTile;
    if (blk < 512) {
        A = word; W = Wn_w; bias = Wn_b; C = ws + OFF_W;
        rowTile = blk >> 3; colTile = blk & 7;
    } else {
        int b2 = blk - 512;
        A = rel; W = Wr_w; bias = Wr_b; C = ws + OFF_R;
        rowTile = b2 >> 3; colTile = b2 & 7;
    }
    const int row0 = rowTile * 32, col0 = colTile * 64;

    __shared__ float As[16][33];   // [k][row], padded
    __shared__ float Bs[16][64];   // [k][col]

    const int tx = t & 15, ty = t >> 4;         // micro: rows ty*2..+1, cols tx*4..+3
    const int lr = t >> 3, lk = (t & 7) << 1;   // A load: row lr, k-pair lk
    const int bk = t >> 4, bc = (t & 15) << 2;  // B load

    float acc[2][4] = {};

    const float* Aptr = A + (size_t)(row0 + lr) * 512 + lk;
    const float* Wptr = W + (size_t)bk * 512 + col0 + bc;
    float2 pa = *(const float2*)Aptr;
    float4 pb = *(const float4*)Wptr;

    for (int k0 = 0; k0 < 512; k0 += 16) {
        As[lk + 0][lr] = pa.x; As[lk + 1][lr] = pa.y;
        *(float4*)&Bs[bk][bc] = pb;
        __syncthreads();
        if (k0 + 16 < 512) {
            pa = *(const float2*)(Aptr + k0 + 16);
            pb = *(const float4*)(Wptr + (size_t)(k0 + 16) * 512);
        }
        #pragma unroll
        for (int kk = 0; kk < 16; kk++) {
            float2 av = *(float2*)&As[kk][ty << 1];
            float4 bv = *(float4*)&Bs[kk][tx << 2];
            float aa[2] = {av.x, av.y};
            float bb[4] = {bv.x, bv.y, bv.z, bv.w};
            #pragma unroll
            for (int i = 0; i < 2; i++)
                #pragma unroll
                for (int j = 0; j < 4; j++)
                    acc[i][j] = fmaf(aa[i], bb[j], acc[i][j]);
        }
        __syncthreads();
    }
    float4 bv = *(const float4*)(bias + col0 + (tx << 2));
    float bb[4] = {bv.x, bv.y, bv.z, bv.w};
    #pragma unroll
    for (int i = 0; i < 2; i++) {
        float4 o;
        o.x = acc[i][0] + bb[0]; o.y = acc[i][1] + bb[1];
        o.z = acc[i][2] + bb[2]; o.w = acc[i][3] + bb[3];
        *(float4*)(C + (size_t)(row0 + (ty << 1) + i) * 512 + col0 + (tx << 2)) = o;
    }
}

// ---------------------------------------------------------------------------
// Kernel 2: attention v5. Block = (b,n), 2048 blocks x 256 threads (4 waves).
// Phase1: wave=16 m, lane=d-octet, shuffle reduce (r1 pattern).
// Phase2: wave=h, lane=m softmax (padded s_lds).
// Phase3: thread=2d, 64-m loop; g written to scratch (NO atomics).
// ---------------------------------------------------------------------------
__global__ __launch_bounds__(256) void attn_kernel(
    const float* __restrict__ mask, float* __restrict__ ws)
{
    __shared__ float s_lds[64][5];    // padded: phase2 reads conflict-free
    __shared__ float wts_lds[64][4];  // phase3 reads are wave-uniform broadcasts

    const int t = threadIdx.x;
    const int lane = t & 63;
    const int wv = __builtin_amdgcn_readfirstlane(t >> 6);
    const int bn = blockIdx.x;
    const int b = bn >> 7;

    const float* wrow  = ws + OFF_W + (size_t)bn * 512;
    const float* rbase = ws + OFF_R + (size_t)b * 32768;
    const float* vbase = ws + OFF_V;

    // ---- Phase 1: s[m,h], wave wv handles m = wv*16..+15, lane = d-octet
    {
        float wreg[8];
        *(float4*)&wreg[0] = *(const float4*)(wrow + lane * 8);
        *(float4*)&wreg[4] = *(const float4*)(wrow + lane * 8 + 4);
        float4 v4[8];
        #pragma unroll
        for (int jj = 0; jj < 8; jj++)
            v4[jj] = *(const float4*)(vbase + (lane * 8 + jj) * 4);

        for (int mi = 0; mi < 16; mi++) {
            int m = wv * 16 + mi;
            const float* rrow = rbase + (size_t)m * 512;
            float rreg[8];
            *(float4*)&rreg[0] = *(const float4*)(rrow + lane * 8);
            *(float4*)&rreg[4] = *(const float4*)(rrow + lane * 8 + 4);
            float a0 = 0.f, a1 = 0.f, a2 = 0.f, a3 = 0.f;
            #pragma unroll
            for (int jj = 0; jj < 8; jj++) {
                float h = fmaxf(wreg[jj] * rreg[jj], 0.f);
                a0 = fmaf(h, v4[jj].x, a0);
                a1 = fmaf(h, v4[jj].y, a1);
                a2 = fmaf(h, v4[jj].z, a2);
                a3 = fmaf(h, v4[jj].w, a3);
            }
            #pragma unroll
            for (int off = 32; off > 0; off >>= 1) {
                a0 += __shfl_xor(a0, off);
                a1 += __shfl_xor(a1, off);
                a2 += __shfl_xor(a2, off);
                a3 += __shfl_xor(a3, off);
            }
            if (lane == 0) {
                s_lds[m][0] = a0; s_lds[m][1] = a1;
                s_lds[m][2] = a2; s_lds[m][3] = a3;
            }
        }
    }
    __syncthreads();

    // ---- Phase 2: softmax per h (wave=h), lane=m
    {
        const int h = wv, m = lane;
        float s = s_lds[m][h];
        float mx = s;
        #pragma unroll
        for (int off = 32; off > 0; off >>= 1)
            mx = fmaxf(mx, __shfl_xor(mx, off));
        float e = expf(s - mx);
        float sum = e;
        #pragma unroll
        for (int off = 32; off > 0; off >>= 1)
            sum += __shfl_xor(sum, off);
        float wt = e / sum * mask[b * 64 + m];
        wts_lds[m][h] = wt;
        float swv = wt;
        #pragma unroll
        for (int off = 32; off > 0; off >>= 1)
            swv += __shfl_xor(swv, off);
        if (m == 0) atomicAdd(&ws[OFF_SW + b * 4 + h], swv);
    }
    __syncthreads();

    // ---- Phase 3: g[h,d] for d = t*2..+1; write scratch (no atomics)
    {
        float2 wd = *(const float2*)(wrow + t * 2);
        float g0[4] = {0.f, 0.f, 0.f, 0.f};
        float g1[4] = {0.f, 0.f, 0.f, 0.f};
        const float* rp = rbase + t * 2;
        #pragma unroll 4
        for (int m = 0; m < 64; m++) {
            float2 rv = *(const float2*)(rp + (size_t)m * 512);
            float4 wt = *(const float4*)&wts_lds[m][0];
            float h0 = fmaxf(wd.x * rv.x, 0.f);
            float h1 = fmaxf(wd.y * rv.y, 0.f);
            g0[0] = fmaf(wt.x, h0, g0[0]); g1[0] = fmaf(wt.x, h1, g1[0]);
            g0[1] = fmaf(wt.y, h0, g0[1]); g1[1] = fmaf(wt.y, h1, g1[1]);
            g0[2] = fmaf(wt.z, h0, g0[2]); g1[2] = fmaf(wt.z, h1, g1[2]);
            g0[3] = fmaf(wt.w, h0, g0[3]); g1[3] = fmaf(wt.w, h1, g1[3]);
        }
        float* sp = ws + OFF_SC + (size_t)bn * 2048;
        #pragma unroll
        for (int h = 0; h < 4; h++)
            *(float2*)&sp[h * 512 + t * 2] = make_float2(g0[h], g1[h]);
    }
}

// ---------------------------------------------------------------------------
// Kernel 3: reduce scratch over n into G. 256 blocks x 256 threads.
// block: b = blk>>4, chunk = (blk&15)>>1 (256 hd-cells), nh = blk&1 (n-half)
// ---------------------------------------------------------------------------
__global__ __launch_bounds__(256) void reduce_g(float* __restrict__ ws)
{
    const int blk = blockIdx.x;
    const int t = threadIdx.x;
    const int b = blk >> 4, sub = blk & 15;
    const int chunk = sub >> 1, nh = sub & 1;
    const float* sp = ws + OFF_SC + ((size_t)b * 128 + nh * 64) * 2048
                    + chunk * 256 + t;
    float acc = 0.f;
    #pragma unroll 8
    for (int n = 0; n < 64; n++)
        acc += sp[(size_t)n * 2048];
    atomicAdd(&ws[OFF_G + b * 2048 + chunk * 256 + t], acc);
}

// ---------------------------------------------------------------------------
// Kernel 4: fused epilogue per batch. 16 blocks x 512 threads.
// ---------------------------------------------------------------------------
__global__ __launch_bounds__(512) void head_kernel(
    const float* __restrict__ lin_w, const float* __restrict__ lin_b,
    const float* __restrict__ final_w, const float* __restrict__ final_b,
    const float* __restrict__ fc_w, const float* __restrict__ fc_b,
    const float* __restrict__ ws, float* __restrict__ out)
{
    const int b = blockIdx.x;
    const int t = threadIdx.x;
    __shared__ float Gs[2048];
    __shared__ float hm[512];
    __shared__ float os[512];
    __shared__ float SWs[4];

    const float* G = ws + OFF_G + (size_t)b * 2048;
    *(float4*)&Gs[t * 4] = *(const float4*)&G[t * 4];
    if (t < 4) SWs[t] = ws[OFF_SW + b * 4 + t];
    __syncthreads();

    {
        const int h = t >> 7, k = t & 127;
        float acc = lin_b[h * 128 + k] * SWs[h];
        const float* lwp = lin_w + ((size_t)h * 512) * 128 + k;
        const float* gp = Gs + h * 512;
        #pragma unroll 8
        for (int d = 0; d < 512; d++)
            acc = fmaf(gp[d], lwp[(size_t)d * 128], acc);
        hm[t] = acc * (1.0f / 128.0f);
    }
    __syncthreads();

    {
        float acc = final_b[t];
        #pragma unroll 8
        for (int d = 0; d < 512; d++)
            acc = fmaf(hm[d], final_w[(size_t)d * 512 + t], acc);
        os[t] = fmaxf(acc, 0.f);
    }
    __syncthreads();

    if (t < 192) {
        int l = t >> 6, ln = t & 63;
        float a = 0.f;
        #pragma unroll 4
        for (int i = ln; i < 512; i += 64)
            a = fmaf(os[i], fc_w[i * 3 + l], a);
        #pragma unroll
        for (int off = 32; off > 0; off >>= 1)
            a += __shfl_xor(a, off);
        if (ln == 0) out[b * 3 + l] = a + fc_b[l];
    }
}

// ---------------------------------------------------------------------------
extern "C" void kernel_launch(void* const* d_in, const int* in_sizes, int n_in,
                              void* d_out, int out_size, void* d_ws, size_t ws_size,
                              hipStream_t stream)
{
    const float* word    = (const float*)d_in[0];
    const float* rel     = (const float*)d_in[1];
    const float* mask    = (const float*)d_in[2];
    const float* Wn_w    = (const float*)d_in[3];
    const float* Wn_b    = (const float*)d_in[4];
    const float* Wr_w    = (const float*)d_in[5];
    const float* Wr_b    = (const float*)d_in[6];
    const float* lin_w   = (const float*)d_in[7];
    const float* lin_b   = (const float*)d_in[8];
    const float* score_w = (const float*)d_in[9];
    // d_in[10] score_b cancels in softmax — unused
    const float* final_w = (const float*)d_in[11];
    const float* final_b = (const float*)d_in[12];
    const float* fc_w    = (const float*)d_in[13];
    const float* fc_b    = (const float*)d_in[14];
    float* ws  = (float*)d_ws;
    float* out = (float*)d_out;

    proj_gemm<<<776, 256, 0, stream>>>(word, rel, Wn_w, Wn_b, Wr_w, Wr_b,
                                       lin_w, score_w, ws);
    attn_kernel<<<2048, 256, 0, stream>>>(mask, ws);
    reduce_g<<<256, 256, 0, stream>>>(ws);
    head_kernel<<<16, 512, 0, stream>>>(lin_w, lin_b, final_w, final_b,
                                        fc_w, fc_b, ws, out);
}